// Round 1
// baseline (281.455 us; speedup 1.0000x reference)
//
#include <hip/hip_runtime.h>
#include <math.h>

#define EMBED 128
#define LDSPAD 136   // 128 + 8 bf16 pad -> 272 B row stride

#define TWO_LOG2E 2.8853900817779268f
#define LOG2E     1.4426950408889634f

typedef __attribute__((ext_vector_type(8))) short short8;
typedef __attribute__((ext_vector_type(4))) float floatx4;
typedef __attribute__((ext_vector_type(4))) unsigned int uint4v;

__device__ __forceinline__ unsigned short f2b(float f) {   // fp32 -> bf16 RNE
    union { float f; unsigned int u; } v; v.f = f;
    unsigned int r = v.u + 0x7FFFu + ((v.u >> 16) & 1u);
    return (unsigned short)(r >> 16);
}

__device__ __forceinline__ float b2f(short u) {
    union { float f; unsigned int i; } v;
    v.i = ((unsigned int)(unsigned short)u) << 16;
    return v.f;
}

// ---------------- K0: cast ent/rel/W to bf16 (rel pre-scaled by 2*log2e) + head histogram ----------------
__global__ __launch_bounds__(256) void k_cast_hist(
    const float* __restrict__ ent, const float* __restrict__ rel, const float* __restrict__ W,
    short* __restrict__ entb, short* __restrict__ relb, short* __restrict__ wb,
    const int* __restrict__ heads, int* __restrict__ cnt,
    int ngE, int ngR, int ngW, int E)
{
    int stride = gridDim.x * 256;
    int total = ngE + ngR + ngW;
    for (int g = blockIdx.x * 256 + threadIdx.x; g < total; g += stride) {
        const float4* src; short* dst; float sc;
        if (g < ngE)            { src = (const float4*)ent + (size_t)g * 2;              dst = entb + (size_t)g * 8;              sc = 1.0f; }
        else if (g < ngE + ngR) { int g2 = g - ngE;       src = (const float4*)rel + (size_t)g2 * 2; dst = relb + (size_t)g2 * 8; sc = TWO_LOG2E; }
        else                    { int g2 = g - ngE - ngR; src = (const float4*)W   + (size_t)g2 * 2; dst = wb   + (size_t)g2 * 8; sc = 1.0f; }
        float4 a = src[0], b = src[1];
        short8 o;
        o[0] = (short)f2b(a.x * sc); o[1] = (short)f2b(a.y * sc);
        o[2] = (short)f2b(a.z * sc); o[3] = (short)f2b(a.w * sc);
        o[4] = (short)f2b(b.x * sc); o[5] = (short)f2b(b.y * sc);
        o[6] = (short)f2b(b.z * sc); o[7] = (short)f2b(b.w * sc);
        *(short8*)dst = o;
    }
    for (int e = blockIdx.x * 256 + threadIdx.x; e < E; e += stride)
        atomicAdd(cnt + heads[e], 1);
}

// ---------------- K1a/b/c: two-level scan (wave-shuffle based) ----------------
__global__ __launch_bounds__(1024) void k_scan1(
    const int* __restrict__ cnt, int* __restrict__ offs,
    int* __restrict__ bsum, int N)
{
    __shared__ int wsum[16];
    const int tid = threadIdx.x;
    int i = blockIdx.x * 1024 + tid;
    int v = (i < N) ? cnt[i] : 0;
    int x = v;
    #pragma unroll
    for (int d = 1; d < 64; d <<= 1) {
        int y = __shfl_up(x, d, 64);
        if ((tid & 63) >= d) x += y;
    }
    if ((tid & 63) == 63) wsum[tid >> 6] = x;
    __syncthreads();
    if (tid < 16) {
        int w = wsum[tid];
        #pragma unroll
        for (int d = 1; d < 16; d <<= 1) {
            int y = __shfl_up(w, d, 16);
            if (tid >= d) w += y;
        }
        wsum[tid] = w;
    }
    __syncthreads();
    int add = (tid >= 64) ? wsum[(tid >> 6) - 1] : 0;
    int incl = x + add;
    if (i < N) offs[i] = incl - v;
    if (tid == 1023) bsum[blockIdx.x] = incl;
}

__global__ __launch_bounds__(1024) void k_scan2(int* __restrict__ bsum, int nb)
{
    __shared__ int wsum[16];
    const int tid = threadIdx.x;
    int v = (tid < nb) ? bsum[tid] : 0;
    int x = v;
    #pragma unroll
    for (int d = 1; d < 64; d <<= 1) {
        int y = __shfl_up(x, d, 64);
        if ((tid & 63) >= d) x += y;
    }
    if ((tid & 63) == 63) wsum[tid >> 6] = x;
    __syncthreads();
    if (tid < 16) {
        int w = wsum[tid];
        #pragma unroll
        for (int d = 1; d < 16; d <<= 1) {
            int y = __shfl_up(w, d, 16);
            if (tid >= d) w += y;
        }
        wsum[tid] = w;
    }
    __syncthreads();
    int add = (tid >= 64) ? wsum[(tid >> 6) - 1] : 0;
    int incl = x + add;
    if (tid < nb) bsum[tid] = incl - v;
}

__global__ __launch_bounds__(256) void k_scan3(
    int* __restrict__ offs, const int* __restrict__ bsum,
    int* __restrict__ cursor, int N)
{
    int i = blockIdx.x * 256 + threadIdx.x;
    if (i < N) {
        int o = offs[i] + bsum[i >> 10];
        offs[i] = o;
        cursor[i] = o;
    }
}

// ---------------- K2: CSR slot-fill: packed (tail, rel) per slot ----------------
__global__ __launch_bounds__(256) void k_csr(
    const int* __restrict__ heads, const int* __restrict__ rels,
    const int* __restrict__ tails, int* __restrict__ cursor,
    int2* __restrict__ tr, int E)
{
    int e = blockIdx.x * 256 + threadIdx.x;
    if (e >= E) return;
    int pos = atomicAdd(cursor + heads[e], 1);
    tr[pos] = make_int2(tails[e], rels[e]);
}

// ---------------- K3: fused score + online-softmax aggregate (log2 domain) ----------------
// 16 lanes per head. relb pre-scaled by 2*log2e; head row scaled at load.
// tanh(h+r) = 1 - 2/(1+exp2(h'+r')).  m, mh stored in log2 domain.
// Per-block max folded into a global atomicMax on an order-preserving uint key.
__global__ __launch_bounds__(256) void k_fused(
    const short* __restrict__ entb, const short* __restrict__ relb,
    const int* __restrict__ offs, const int* __restrict__ cnt,
    const int2* __restrict__ tr,
    short* __restrict__ accb, float* __restrict__ mh, float* __restrict__ lh,
    unsigned int* __restrict__ Mbits, int N, int R)
{
    __shared__ short rl[64 * EMBED];   // 16 KB rel table cache (already exp2-scaled)
    const int tid = threadIdx.x;
    if (R <= 64) {
        int nch = R * 16;
        for (int i = tid; i < nch; i += 256)
            ((short8*)rl)[i] = ((const short8*)relb)[i];
    }
    __syncthreads();
    const short* relsrc = (R <= 64) ? (const short*)rl : relb;

    const int lane = tid & 15;
    int head = blockIdx.x * 16 + (tid >> 4);
    float m = -INFINITY;
    if (head < N) {
        int start = offs[head];
        int c     = cnt[head];
        uint4v hu = *((const uint4v*)(entb + (size_t)head * EMBED) + lane);
        float hf[8];
        #pragma unroll
        for (int p = 0; p < 4; ++p) {
            hf[2*p]   = __uint_as_float(hu[p] << 16)          * TWO_LOG2E;
            hf[2*p+1] = __uint_as_float(hu[p] & 0xFFFF0000u)  * TWO_LOG2E;
        }
        float l = 0.f;
        float acc[8] = {0,0,0,0,0,0,0,0};
        for (int base = 0; base < c; base += 16) {
            int rem = c - base;
            int mm  = rem < 16 ? rem : 16;
            int2 trv = make_int2(0, 0);
            if (lane < mm) trv = tr[start + base + lane];
            // prefetch first tail row of the chunk
            int t0 = __shfl(trv.x, 0, 16);
            uint4v vtn = *((const uint4v*)(entb + (size_t)t0 * EMBED) + lane);
            for (int j = 0; j < mm; ++j) {
                uint4v vt = vtn;
                if (j + 1 < mm) {           // software-pipeline next tail gather
                    int t2 = __shfl(trv.x, j + 1, 16);
                    vtn = *((const uint4v*)(entb + (size_t)t2 * EMBED) + lane);
                }
                int r = __shfl(trv.y, j, 16);
                uint4v ru = *((const uint4v*)(relsrc + (size_t)r * EMBED) + lane);
                float S = 0.f;
                float vtf[8];
                #pragma unroll
                for (int p = 0; p < 4; ++p) {
                    unsigned int tu = vt[p], rr = ru[p];
                    float tlo = __uint_as_float(tu << 16);
                    float thi = __uint_as_float(tu & 0xFFFF0000u);
                    float xlo = hf[2*p]   + __uint_as_float(rr << 16);
                    float xhi = hf[2*p+1] + __uint_as_float(rr & 0xFFFF0000u);
                    float elo = exp2f(xlo);
                    float ehi = exp2f(xhi);
                    float clo = __builtin_amdgcn_rcpf(1.0f + elo);
                    float chi = __builtin_amdgcn_rcpf(1.0f + ehi);
                    S += tlo * (1.0f - 2.0f * clo);
                    S += thi * (1.0f - 2.0f * chi);
                    vtf[2*p]   = tlo;
                    vtf[2*p+1] = thi;
                }
                S += __shfl_xor(S, 1, 16);
                S += __shfl_xor(S, 2, 16);
                S += __shfl_xor(S, 4, 16);
                S += __shfl_xor(S, 8, 16);
                float s2    = S * LOG2E;            // log2-domain score
                float mn    = fmaxf(m, s2);
                float alpha = exp2f(m - mn);        // m=-inf first edge -> 0
                float p     = exp2f(s2 - mn);
                l = l * alpha + p;
                #pragma unroll
                for (int q = 0; q < 8; ++q)
                    acc[q] = acc[q] * alpha + p * vtf[q];
                m = mn;
            }
        }
        short8 o;
        #pragma unroll
        for (int q = 0; q < 8; ++q) o[q] = (short)f2b(acc[q]);
        *((short8*)(accb + (size_t)head * EMBED) + lane) = o;
        if (lane == 0) { mh[head] = m; lh[head] = l; }
    }
    __shared__ float smax[256];
    smax[tid] = m;
    __syncthreads();
    for (int off = 128; off > 0; off >>= 1) {
        if (tid < off) smax[tid] = fmaxf(smax[tid], smax[tid + off]);
        __syncthreads();
    }
    if (tid == 0) {
        unsigned int u = __float_as_uint(smax[0]);
        unsigned int key = (u & 0x80000000u) ? ~u : (u | 0x80000000u);
        atomicMax(Mbits, key);
    }
}

// ---------------- K4: fused normalize + x = ent + agg + bf16 MFMA GEMM ----------------
// inv = 1/(lh + 1e-10*exp2(M2 - mh2)); out = leaky_relu((ent + acc*inv) @ W^T)
__global__ __launch_bounds__(256) void k_gemm_f(
    const short* __restrict__ entb, const short* __restrict__ accb,
    const float* __restrict__ mh, const float* __restrict__ lh,
    const unsigned int* __restrict__ Mbits, const short* __restrict__ wb,
    float* __restrict__ out, int N)
{
    __shared__ short xs[128 * LDSPAD];
    __shared__ short ws[128 * LDSPAD];
    const int tid = threadIdx.x;
    const int n0  = blockIdx.x * 128;
    unsigned int k = Mbits[0];
    const float M2 = (k & 0x80000000u) ? __uint_as_float(k & 0x7FFFFFFFu)
                                       : __uint_as_float(~k);

    // stage W (pre-cast bf16): 2048 short8 chunks, 8 per thread
    #pragma unroll
    for (int it = 0; it < 8; ++it) {
        int ch = it * 256 + tid;
        int row = ch >> 4, col8 = ch & 15;
        *(short8*)(ws + row * LDSPAD + col8 * 8) = ((const short8*)wb)[ch];
    }
    // stage x = ent + acc*inv: 2048 short8 chunks, 8 per thread
    #pragma unroll
    for (int it = 0; it < 8; ++it) {
        int ch = it * 256 + tid;
        int row = ch >> 4, col8 = ch & 15;
        int g = n0 + row;
        short8 v = {0,0,0,0,0,0,0,0};
        if (g < N) {
            float inv = 1.0f / (lh[g] + 1e-10f * exp2f(M2 - mh[g]));  // inf -> 0 (degenerate head)
            short8 e8 = *((const short8*)(entb + (size_t)g * EMBED) + col8);
            short8 a8 = *((const short8*)(accb + (size_t)g * EMBED) + col8);
            #pragma unroll
            for (int q = 0; q < 8; ++q)
                v[q] = (short)f2b(b2f(e8[q]) + b2f(a8[q]) * inv);
        }
        *(short8*)(xs + row * LDSPAD + col8 * 8) = v;
    }
    __syncthreads();

    const int wv   = tid >> 6;
    const int lane = tid & 63;
    const int n16  = lane & 15;
    const int quad = lane >> 4;

    floatx4 acc[2][8];
    #pragma unroll
    for (int rt = 0; rt < 2; ++rt)
        #pragma unroll
        for (int jt = 0; jt < 8; ++jt)
            acc[rt][jt] = (floatx4){0.f, 0.f, 0.f, 0.f};

    #pragma unroll
    for (int kc = 0; kc < 4; ++kc) {
        int koff = kc * 32 + quad * 8;
        short8 a0 = *(const short8*)(xs + (wv * 32      + n16) * LDSPAD + koff);
        short8 a1 = *(const short8*)(xs + (wv * 32 + 16 + n16) * LDSPAD + koff);
        #pragma unroll
        for (int jt = 0; jt < 8; ++jt) {
            short8 b = *(const short8*)(ws + (jt * 16 + n16) * LDSPAD + koff);
            acc[0][jt] = __builtin_amdgcn_mfma_f32_16x16x32_bf16(a0, b, acc[0][jt], 0, 0, 0);
            acc[1][jt] = __builtin_amdgcn_mfma_f32_16x16x32_bf16(a1, b, acc[1][jt], 0, 0, 0);
        }
    }

    #pragma unroll
    for (int rt = 0; rt < 2; ++rt) {
        int rowbase = n0 + wv * 32 + rt * 16 + quad * 4;
        #pragma unroll
        for (int r = 0; r < 4; ++r) {
            int grow = rowbase + r;
            if (grow < N) {
                float* o = out + (size_t)grow * EMBED + n16;
                #pragma unroll
                for (int jt = 0; jt < 8; ++jt) {
                    float v = acc[rt][jt][r];
                    o[jt * 16] = (v > 0.f) ? v : 0.2f * v;
                }
            }
        }
    }
}

extern "C" void kernel_launch(void* const* d_in, const int* in_sizes, int n_in,
                              void* d_out, int out_size, void* d_ws, size_t ws_size,
                              hipStream_t stream)
{
    const float* ent   = (const float*)d_in[0];   // entity_emb  [N,128] fp32
    const float* rel   = (const float*)d_in[1];   // rel_embed   [R,128] fp32
    const float* W     = (const float*)d_in[2];   // W           [128,128] fp32
    const int*   heads = (const int*)d_in[3];
    const int*   rels  = (const int*)d_in[4];
    const int*   tails = (const int*)d_in[5];
    const int E = in_sizes[3];
    const int N = in_sizes[0] / EMBED;
    const int R = in_sizes[1] / EMBED;
    float* out = (float*)d_out;

    // ws layout (same footprint as previous version):
    // accb[N*128]s | mh[N]f | lh[N]f | tr[E]int2 | cnt[N]i | offs[N]i | cursor[N]i |
    // wb[16384]s (32KB, was blockmax) | bsum[1024]i | Mbits[4]u (16B pad) | entb[N*128]s | relb[R*128]s
    short* accb        = (short*)d_ws;
    float* mh          = (float*)(accb + (size_t)N * EMBED);
    float* lh          = mh + N;
    int2*  tr          = (int2*)(lh + N);
    int*   cnt         = (int*)(tr + E);
    int*   offs        = cnt + N;
    int*   cursor      = offs + N;
    short* wb          = (short*)(cursor + N);          // 128*128 bf16 = 32 KB
    int*   bsum        = (int*)(wb + 16384);            // 1024 ints
    unsigned int* Mbits = (unsigned int*)(bsum + 1024); // 16 B slot (alignment pad)
    short* entb        = (short*)(Mbits + 4);
    short* relb        = entb + (size_t)N * EMBED;

    const int nb  = (N + 1023) >> 10;       // scan blocks
    const int ngh = (N + 15) / 16;          // per-head group blocks

    hipMemsetAsync(cnt, 0, (size_t)N * sizeof(int), stream);
    hipMemsetAsync((void*)Mbits, 0, sizeof(unsigned int), stream);

    int ngE = N * EMBED / 8, ngR = R * EMBED / 8, ngW = EMBED * EMBED / 8;
    k_cast_hist<<<2048, 256, 0, stream>>>(ent, rel, W, entb, relb, wb, heads, cnt, ngE, ngR, ngW, E);
    k_scan1<<<nb, 1024, 0, stream>>>(cnt, offs, bsum, N);
    k_scan2<<<1, 1024, 0, stream>>>(bsum, nb);
    k_scan3<<<(N + 255) / 256, 256, 0, stream>>>(offs, bsum, cursor, N);
    k_csr<<<(E + 255) / 256, 256, 0, stream>>>(heads, rels, tails, cursor, tr, E);
    k_fused<<<ngh, 256, 0, stream>>>(entb, relb, offs, cnt, tr, accb, mh, lh, Mbits, N, R);
    k_gemm_f<<<(N + 127) / 128, 256, 0, stream>>>(entb, accb, mh, lh, Mbits, wb, out, N);
}